// Round 25
// baseline (654.180 us; speedup 1.0000x reference)
//
#include <hip/hip_runtime.h>
#include <hip/hip_bf16.h>
#include <math.h>

#define C_IN   32
#define D0     64
#define H0     96
#define W0     192
#define DD     193
#define HH     288
#define WW     576
#define NPIX   (HH*WW)            // 165888
#define NPIX2  (NPIX/2)           // 82944
#define NPIX4  (NPIX/4)           // 41472
#define NVOL   ((size_t)DD*NPIX)  // 32,016,384
#define NVOL2  (NVOL/2)
#define NCOST  (D0*H0*W0)         // 1,179,648
#define NCOST4 (NCOST/4)          // 294912

typedef float v2f __attribute__((ext_vector_type(2)));

__device__ __forceinline__ float2 f2(float x, float y) { float2 r; r.x = x; r.y = y; return r; }

// packed f32 FMA: d = a*b + c in one v_pk_fma_f32
__device__ __forceinline__ v2f fma2(v2f a, v2f b, v2f c) {
#if __has_builtin(__builtin_elementwise_fma)
    return __builtin_elementwise_fma(a, b, c);
#else
    asm("v_pk_fma_f32 %0, %1, %2, %0" : "+v"(c) : "v"(a), "v"(b));
    return c;
#endif
}

// bf16 storage helpers (RNE pack, shift unpack); compute stays f32
__device__ __forceinline__ unsigned short f2bf(float f) {
    unsigned u = __float_as_uint(f);
    unsigned r = (u + 0x7FFFu + ((u >> 16) & 1u)) >> 16;
    return (unsigned short)r;
}
__device__ __forceinline__ unsigned packbf(float x, float y) {
    return (unsigned)f2bf(x) | ((unsigned)f2bf(y) << 16);
}
__device__ __forceinline__ float bflo(unsigned u) { return __uint_as_float(u << 16); }
__device__ __forceinline__ float bfhi(unsigned u) { return __uint_as_float(u & 0xFFFF0000u); }
__device__ __forceinline__ float bf2f(unsigned short s) { return __uint_as_float((unsigned)s << 16); }

// ---------------- LDS-tiled conv3d, channel-split x4, bf16 LDS staging (R25)
// LDS halves (34.8->17.4 KB/block) -> LDS-allowed blocks/CU doubles, attacking
// the latency-bound staging stall with TLP. Taps read u16 + shift-convert.
#define CZC   8
#define CSL   (CZC + 2)
#define CROWS 6
#define CSTR  72

__global__ __launch_bounds__(256)
void conv3d_split_kernel(const float* __restrict__ x,
                         const float* __restrict__ w,
                         float* __restrict__ partial) {
    __shared__ __align__(16) unsigned short sb[2][CSL][CROWS][CSTR];
    const int tid = threadIdx.x;
    const int tx = tid & 63, ty = tid >> 6;
    const int wb = blockIdx.x * 64, hb = blockIdx.y * 4;
    const int zc = blockIdx.z & 7, part = blockIdx.z >> 3;
    const int z0 = zc * CZC;
    const int cbase = part * 8;

    float acc[CZC];
    #pragma unroll
    for (int i = 0; i < CZC; ++i) acc[i] = 0.f;

    // STAGE: load f32 halo, convert to bf16 at commit (consumed immediately —
    // non-pipelined structure, so no in-flight requirement is broken).
    #define STAGE(b, ci)                                                          \
    {                                                                             \
        const float* xc = x + (size_t)(ci) * (D0 * H0 * W0);                      \
        _Pragma("unroll")                                                         \
        for (int t0 = 0; t0 < 4; ++t0) {                                          \
            int t = t0 * 256 + tid;                                               \
            if (t < 960) {                                                        \
                int sl = t / 96; int rem = t - sl * 96;                           \
                int r = rem >> 4, v = rem & 15;                                   \
                int zz = z0 - 1 + sl, hh = hb - 1 + r;                            \
                bool ok = (unsigned)zz < (unsigned)D0 && (unsigned)hh < (unsigned)H0; \
                float4 val = {0.f, 0.f, 0.f, 0.f};                                \
                if (ok) val = *(const float4*)(xc + ((size_t)zz * H0 + hh) * W0 + wb + 4 * v); \
                ushort4 pv;                                                       \
                pv.x = f2bf(val.x); pv.y = f2bf(val.y);                           \
                pv.z = f2bf(val.z); pv.w = f2bf(val.w);                           \
                *(ushort4*)&sb[b][sl][r][4 + 4 * v] = pv;                         \
            }                                                                     \
        }                                                                         \
        if (tid < 120) {                                                          \
            int sl = tid / 12; int e = tid - sl * 12;                             \
            int r = e >> 1, side = e & 1;                                         \
            int zz = z0 - 1 + sl, hh = hb - 1 + r;                                \
            int ww = side ? wb + 64 : wb - 1;                                     \
            bool ok = (unsigned)zz < (unsigned)D0 && (unsigned)hh < (unsigned)H0  \
                      && (unsigned)ww < (unsigned)W0;                             \
            sb[b][sl][r][side ? 68 : 3] = ok ? f2bf(xc[((size_t)zz * H0 + hh) * W0 + ww]) : (unsigned short)0; \
        }                                                                         \
    }

    STAGE(0, cbase);
    __syncthreads();

    for (int c = 0; c < 8; ++c) {
        const int b = c & 1;
        if (c + 1 < 8) STAGE(b ^ 1, cbase + c + 1);

        const float* wc = w + (cbase + c) * 27;
        float wr[27];
        #pragma unroll
        for (int t = 0; t < 27; ++t) wr[t] = wc[t];

        #pragma unroll
        for (int sl = 0; sl < CSL; ++sl) {
            float tap[9];
            #pragma unroll
            for (int i = 0; i < 3; ++i)
                #pragma unroll
                for (int j = 0; j < 3; ++j)
                    tap[i * 3 + j] = bf2f(sb[b][sl][ty + i][tx + 3 + j]);
            if (sl < CZC) {
                float cs = 0.f;
                #pragma unroll
                for (int t = 0; t < 9; ++t) cs += wr[t] * tap[t];
                acc[sl] += cs;
            }
            if (sl >= 1 && sl - 1 < CZC) {
                float cs = 0.f;
                #pragma unroll
                for (int t = 0; t < 9; ++t) cs += wr[9 + t] * tap[t];
                acc[sl - 1] += cs;
            }
            if (sl >= 2) {
                float cs = 0.f;
                #pragma unroll
                for (int t = 0; t < 9; ++t) cs += wr[18 + t] * tap[t];
                acc[sl - 2] += cs;
            }
        }
        __syncthreads();
    }
    #undef STAGE

    float* po = partial + (size_t)part * NCOST;
    #pragma unroll
    for (int i = 0; i < CZC; ++i)
        po[((size_t)(z0 + i) * H0 + (hb + ty)) * W0 + (wb + tx)] = acc[i];
}

// ---------------- combine 4 partials -> cost (float4)
__global__ void combine_kernel(const float4* __restrict__ partial, float4* __restrict__ cost) {
    int i = blockIdx.x * 256 + threadIdx.x;
    if (i >= NCOST4) return;
    float4 a = partial[i];
    float4 b = partial[i + NCOST4];
    float4 c = partial[i + 2 * NCOST4];
    float4 d = partial[i + 3 * NCOST4];
    float4 r;
    r.x = a.x + b.x + c.x + d.x;
    r.y = a.y + b.y + c.y + d.y;
    r.z = a.z + b.z + c.z + d.z;
    r.w = a.w + b.w + c.w + d.w;
    cost[i] = r;
}

// ---------------- fused L1-norm + pre-normalize guidance to packed bf16
__global__ void gnorm_kernel(const float* __restrict__ g, unsigned* __restrict__ gn) {
    int p = blockIdx.x * 256 + threadIdx.x;   // pixel-pair index
    if (p >= NPIX2) return;
    float sx = 0.f, sy = 0.f;
    for (int c = 0; c < 75; ++c) {
        float2 v = *(const float2*)&g[(size_t)c * NPIX + 2 * p];
        sx += fabsf(v.x); sy += fabsf(v.y);
    }
    float ix = 1.0f / fmaxf(sx, 1e-12f);
    float iy = 1.0f / fmaxf(sy, 1e-12f);
    for (int c = 0; c < 75; ++c) {
        float2 v = *(const float2*)&g[(size_t)c * NPIX + 2 * p];
        gn[(size_t)c * NPIX2 + p] = packbf(v.x * ix, v.y * iy);
    }
}

// ---------------- trilinear resize cost f32 -> vol bf16, 2 px/thread (packed u32 store)
__global__ void resize_kernel(const float* __restrict__ cost, unsigned* __restrict__ out) {
    size_t idx2 = (size_t)blockIdx.x * 256 + threadIdx.x;
    if (idx2 >= NVOL2) return;
    size_t idx = idx2 * 2;
    int w = (int)(idx % WW);          // even; w+1 in same row (WW even)
    int t = (int)(idx / WW);
    int h = t % HH;
    int d = t / HH;

    float sd = fminf(fmaxf((d + 0.5f) * (64.0f / 193.0f) - 0.5f, 0.0f), 63.0f);
    int d0 = (int)floorf(sd); int d1 = min(d0 + 1, 63); float fd = sd - (float)d0;
    float sh = fminf(fmaxf((h + 0.5f) * (96.0f / 288.0f) - 0.5f, 0.0f), 95.0f);
    int h0 = (int)floorf(sh); int h1 = min(h0 + 1, 95); float fh = sh - (float)h0;

    float r01[2];
    #pragma unroll
    for (int k = 0; k < 2; ++k) {
        float sw = fminf(fmaxf((w + k + 0.5f) * (192.0f / 576.0f) - 0.5f, 0.0f), 191.0f);
        int w0 = (int)floorf(sw); int w1 = min(w0 + 1, 191); float fw = sw - (float)w0;
        #define CV(dz, hy, wx) cost[((size_t)(dz) * H0 + (hy)) * W0 + (wx)]
        float v000 = CV(d0, h0, w0), v001 = CV(d0, h0, w1);
        float v010 = CV(d0, h1, w0), v011 = CV(d0, h1, w1);
        float v100 = CV(d1, h0, w0), v101 = CV(d1, h0, w1);
        float v110 = CV(d1, h1, w0), v111 = CV(d1, h1, w1);
        #undef CV
        float a = v000 * (1.f - fw) + v001 * fw;
        float b = v010 * (1.f - fw) + v011 * fw;
        float c = v100 * (1.f - fw) + v101 * fw;
        float e = v110 * (1.f - fw) + v111 * fw;
        float lo = a * (1.f - fh) + b * fh;
        float hi = c * (1.f - fh) + e * fh;
        r01[k] = lo * (1.f - fd) + hi * fd;
    }
    out[idx2] = packbf(r01[0], r01[1]);
}

// ---------------- LDS-tiled LGA pass: R20 configuration (measured local optimum:
// NDCH 2->112us, 3->96us, 4->111us per pass).
#define TW 64
#define TH 8
#define LROWS 12
#define LSTR  72
#define SLC_PAD 880
#define NTHR 256
#define DCHUNK 65
#define NDCH  3

template<int MODE, bool SCALED>
__global__ __launch_bounds__(NTHR, 2)
void lga_tiled_kernel(const unsigned short* __restrict__ in, unsigned short* __restrict__ out,
                      const unsigned* __restrict__ gn,
                      const float* __restrict__ inscale,
                      float* __restrict__ accAbuf, float* __restrict__ accSbuf) {
    __shared__ __align__(16) float sbuf[8][SLC_PAD];
    const int tid = threadIdx.x;
    const int tx = tid & 31, ty = tid >> 5;
    const int wb = blockIdx.x * TW, hb = blockIdx.y * TH;
    const int pix0 = (hb + ty) * WW + (wb + 2 * tx);
    const int ds = blockIdx.z * DCHUNK;
    const int de = min(ds + DCHUNK, DD);
    const int e0 = max(ds - 1, 0);
    const int emax = min(de, DD - 1);

    const bool hasB = (tid < 128);
    const bool hasE = (tid >= 128 && tid < 224);

    int slcA, vdstA; size_t vgoffA; bool vokA;
    {
        slcA = tid / 96; int u = tid - slcA * 96;
        int r = u >> 3, v = u & 7;
        int hh = hb - 2 + r;
        vokA = (unsigned)hh < (unsigned)HH;
        vgoffA = vokA ? (size_t)hh * WW + wb + 8 * v : 0;
        vdstA = r * LSTR + 4 + 8 * v;
    }
    int slcB = 0, vdstB = 0; size_t vgoffB = 0; bool vokB = false;
    if (hasB) {
        int t = tid + 256; slcB = t / 96; int u = t - slcB * 96;
        int r = u >> 3, v = u & 7;
        int hh = hb - 2 + r;
        vokB = (unsigned)hh < (unsigned)HH;
        vgoffB = vokB ? (size_t)hh * WW + wb + 8 * v : 0;
        vdstB = r * LSTR + 4 + 8 * v;
    }
    int slcE = 0, edstE = 0; size_t egoffE = 0; bool eokE = false;
    if (hasE) {
        int t = tid - 128; slcE = t / 24; int u = t - slcE * 24;
        int r = u >> 1, side = u & 1;
        int hh = hb - 2 + r;
        int gc = side ? wb + 64 : wb - 2;
        eokE = (unsigned)hh < (unsigned)HH && (unsigned)gc < (unsigned)WW;
        egoffE = eokE ? (size_t)hh * WW + gc : 0;
        edstE = r * LSTR + (side ? 68 : 2);
    }

    // inscale factors (only in the SCALED instantiation)
    float is8A[8], is8B[8]; float2 isE = f2(1.f, 1.f);
    if constexpr (SCALED) {
        #pragma unroll
        for (int j = 0; j < 8; ++j) { is8A[j] = 1.f; is8B[j] = 1.f; }
        if (vokA) {
            float4 a = *(const float4*)&inscale[vgoffA];
            float4 b = *(const float4*)&inscale[vgoffA + 4];
            is8A[0]=a.x; is8A[1]=a.y; is8A[2]=a.z; is8A[3]=a.w;
            is8A[4]=b.x; is8A[5]=b.y; is8A[6]=b.z; is8A[7]=b.w;
        }
        if (hasB && vokB) {
            float4 a = *(const float4*)&inscale[vgoffB];
            float4 b = *(const float4*)&inscale[vgoffB + 4];
            is8B[0]=a.x; is8B[1]=a.y; is8B[2]=a.z; is8B[3]=a.w;
            is8B[4]=b.x; is8B[5]=b.y; is8B[6]=b.z; is8B[7]=b.w;
        }
        if (hasE && eokE) isE = *(const float2*)&inscale[egoffE];
    }

    // --- pre-normalized guidance weights, (px0,px1) packed as v2f
    const int gp = pix0 >> 1;
    v2f g0[25], g1[25], g2[25];
    #pragma unroll
    for (int c = 0; c < 25; ++c) {
        unsigned u = gn[(size_t)c * NPIX2 + gp];
        g0[c] = (v2f){bflo(u), bfhi(u)};
    }
    #pragma unroll
    for (int c = 0; c < 25; ++c) {
        unsigned u = gn[(size_t)(25 + c) * NPIX2 + gp];
        g1[c] = (v2f){bflo(u), bfhi(u)};
    }
    #pragma unroll
    for (int c = 0; c < 25; ++c) {
        unsigned u = gn[(size_t)(50 + c) * NPIX2 + gp];
        g2[c] = (v2f){bflo(u), bfhi(u)};
    }

    // pending RAW bf16 loads
    uint4 avA = {0u,0u,0u,0u}, avB = {0u,0u,0u,0u};
    unsigned aeE = 0u;

    #define LOADQUAD(eb)                                                          \
    {                                                                             \
        if (vokA && (eb) + slcA <= emax)                                          \
            avA = *(const uint4*)(in + (size_t)((eb) + slcA) * NPIX + vgoffA);    \
        if (hasB && vokB && (eb) + slcB <= emax)                                  \
            avB = *(const uint4*)(in + (size_t)((eb) + slcB) * NPIX + vgoffB);    \
        if (hasE && eokE && (eb) + slcE <= emax)                                  \
            aeE = *(const unsigned*)(in + (size_t)((eb) + slcE) * NPIX + egoffE); \
    }

    LOADQUAD(e0);

    v2f accA = {0.f, 0.f}, accB = {0.f, 0.f};
    float2 aloc = f2(0.f, 0.f), sloc = f2(0.f, 0.f);
    unsigned* ou32 = (unsigned*)out;

    #define EMIT(n, vx, vy)                                                       \
    {                                                                             \
        if constexpr (MODE == 0) {                                                \
            ou32[((size_t)(n) * NPIX + pix0) >> 1] = packbf((vx), (vy));          \
        } else if constexpr (MODE == 1) {                                         \
            float ex_ = __expf(-(vx)), ey_ = __expf(-(vy));                       \
            ou32[((size_t)(n) * NPIX + pix0) >> 1] = packbf(ex_, ey_);            \
            sloc.x += ex_; sloc.y += ey_;                                         \
        } else {                                                                  \
            aloc.x += (vx) * (float)(n); aloc.y += (vy) * (float)(n);             \
            sloc.x += fabsf(vx); sloc.y += fabsf(vy);                             \
        }                                                                         \
    }

    for (int e = e0; e <= emax; e += 4) {
        // 1. commit pending quad: bf16->f32 (+inscale) at consume time
        {
            float v0 = bflo(avA.x), v1 = bfhi(avA.x), v2 = bflo(avA.y), v3 = bfhi(avA.y);
            float v4 = bflo(avA.z), v5 = bfhi(avA.z), v6 = bflo(avA.w), v7 = bfhi(avA.w);
            if constexpr (SCALED) {
                v0 *= is8A[0]; v1 *= is8A[1]; v2 *= is8A[2]; v3 *= is8A[3];
                v4 *= is8A[4]; v5 *= is8A[5]; v6 *= is8A[6]; v7 *= is8A[7];
            }
            float* sp = &sbuf[(e + slcA) & 7][vdstA];
            *(float4*)sp       = make_float4(v0, v1, v2, v3);
            *(float4*)(sp + 4) = make_float4(v4, v5, v6, v7);
        }
        if (hasB) {
            float v0 = bflo(avB.x), v1 = bfhi(avB.x), v2 = bflo(avB.y), v3 = bfhi(avB.y);
            float v4 = bflo(avB.z), v5 = bfhi(avB.z), v6 = bflo(avB.w), v7 = bfhi(avB.w);
            if constexpr (SCALED) {
                v0 *= is8B[0]; v1 *= is8B[1]; v2 *= is8B[2]; v3 *= is8B[3];
                v4 *= is8B[4]; v5 *= is8B[5]; v6 *= is8B[6]; v7 *= is8B[7];
            }
            float* sp = &sbuf[(e + slcB) & 7][vdstB];
            *(float4*)sp       = make_float4(v0, v1, v2, v3);
            *(float4*)(sp + 4) = make_float4(v4, v5, v6, v7);
        }
        if (hasE) {
            float v0 = bflo(aeE), v1 = bfhi(aeE);
            if constexpr (SCALED) { v0 *= isE.x; v1 *= isE.y; }
            float* sp = &sbuf[(e + slcE) & 7][edstE];
            *(float2*)sp = f2(v0, v1);
        }
        // 2. issue RAW loads for the next quad
        LOADQUAD(e + 4);
        // 3. LDS drain + raw barrier (no vmcnt drain)
        asm volatile("s_waitcnt lgkmcnt(0)" ::: "memory");
        __builtin_amdgcn_s_barrier();
        // 4. compute up to 4 slices (packed-f32: 3 pk_fma per tap for 2 px x 3 convs)
        #pragma unroll
        for (int ss = 0; ss < 4; ++ss) {
            int f = e + ss;
            if (f > emax) break;
            const float* base = sbuf[f & 7] + ty * LSTR + 2 * tx + 2;
            v2f a0 = {0.f, 0.f}, a1 = {0.f, 0.f}, a2 = {0.f, 0.f};
            #pragma unroll
            for (int i = 0; i < 5; ++i) {
                const float* rp = base + i * LSTR;
                v2f W01 = *(const v2f*)(rp);
                v2f W23 = *(const v2f*)(rp + 2);
                v2f W45 = *(const v2f*)(rp + 4);
                v2f W12 = {rp[1], rp[2]};
                v2f W34 = {rp[3], rp[4]};
                int t = i * 5;
                a0 = fma2(g0[t],     W01, a0); a1 = fma2(g1[t],     W01, a1); a2 = fma2(g2[t],     W01, a2);
                a0 = fma2(g0[t + 1], W12, a0); a1 = fma2(g1[t + 1], W12, a1); a2 = fma2(g2[t + 1], W12, a2);
                a0 = fma2(g0[t + 2], W23, a0); a1 = fma2(g1[t + 2], W23, a1); a2 = fma2(g2[t + 2], W23, a2);
                a0 = fma2(g0[t + 3], W34, a0); a1 = fma2(g1[t + 3], W34, a1); a2 = fma2(g2[t + 3], W34, a2);
                a0 = fma2(g0[t + 4], W45, a0); a1 = fma2(g1[t + 4], W45, a1); a2 = fma2(g2[t + 4], W45, a2);
            }
            int n = f - 1;
            if (n >= ds && n < de) {
                v2f rr = accA + a2;
                EMIT(n, rr.x, rr.y);
            }
            accA = accB + a1;
            accB = a0;
        }
    }
    if (de == DD) {
        EMIT(DD - 1, accA.x, accA.y);  // slice DD is zero-pad: no c2 term
    }
    #undef EMIT
    #undef LOADQUAD

    if constexpr (MODE == 1) {
        atomicAdd(&accSbuf[pix0], sloc.x);
        atomicAdd(&accSbuf[pix0 + 1], sloc.y);
    } else if constexpr (MODE == 2) {
        atomicAdd(&accAbuf[pix0], aloc.x);
        atomicAdd(&accAbuf[pix0 + 1], aloc.y);
        atomicAdd(&accSbuf[pix0], sloc.x);
        atomicAdd(&accSbuf[pix0 + 1], sloc.y);
    }
}

// ---------------- reciprocal in place (float4)
__global__ void rcp_kernel(float4* __restrict__ v) {
    int p = blockIdx.x * 256 + threadIdx.x;
    if (p >= NPIX4) return;
    float4 a = v[p];
    a.x = 1.0f / a.x; a.y = 1.0f / a.y; a.z = 1.0f / a.z; a.w = 1.0f / a.w;
    v[p] = a;
}

// ---------------- finish: out = A / max(S, eps) (float4)
__global__ void finish_kernel(const float4* __restrict__ A, const float4* __restrict__ S,
                              float4* __restrict__ out) {
    int p = blockIdx.x * 256 + threadIdx.x;
    if (p >= NPIX4) return;
    float4 a = A[p], s = S[p];
    float4 r;
    r.x = a.x / fmaxf(s.x, 1e-12f);
    r.y = a.y / fmaxf(s.y, 1e-12f);
    r.z = a.z / fmaxf(s.z, 1e-12f);
    r.w = a.w / fmaxf(s.w, 1e-12f);
    out[p] = r;
}

extern "C" void kernel_launch(void* const* d_in, const int* in_sizes, int n_in,
                              void* d_out, int out_size, void* d_ws, size_t ws_size,
                              hipStream_t stream) {
    const float* x    = (const float*)d_in[0];
    const float* lg1  = (const float*)d_in[1];
    const float* lg2  = (const float*)d_in[2];
    const float* cw   = (const float*)d_in[3];
    float* out = (float*)d_out;

    float* ws   = (float*)d_ws;
    // bf16 volumes: NVOL ushorts = NVOL/2 float slots each
    unsigned short* buf0 = (unsigned short*)ws;
    unsigned short* buf1 = (unsigned short*)(ws + NVOL / 2);
    float* cost = ws + NVOL;           // after both bf16 volumes
    float* rden = cost + NCOST;
    float* Abuf = rden + NPIX;
    float* Sbuf = Abuf + NPIX;
    unsigned* gn1 = (unsigned*)(Sbuf + NPIX);
    unsigned* gn2 = gn1 + (size_t)75 * NPIX2;
    // conv partials (4 x NCOST f32) alias buf1's region (dead before lga#1 writes buf1)
    float* partials = (float*)buf1;

    const dim3 lgrid(WW / TW, HH / TH, NDCH);

    // 0. zero the atomic accumulators
    hipMemsetAsync(rden, 0, NPIX * sizeof(float), stream);
    hipMemsetAsync(Abuf, 0, NPIX * sizeof(float), stream);
    hipMemsetAsync(Sbuf, 0, NPIX * sizeof(float), stream);

    // 1. conv3d (channel-split x4, bf16 LDS staging) + combine
    conv3d_split_kernel<<<dim3(W0 / 64, H0 / 4, (D0 / CZC) * 4), 256, 0, stream>>>(x, cw, partials);
    combine_kernel<<<(NCOST4 + 255) / 256, 256, 0, stream>>>((const float4*)partials, (float4*)cost);
    // 2. fused L1-norm + bf16 pre-normalized guidance
    gnorm_kernel<<<(NPIX2 + 255) / 256, 256, 0, stream>>>(lg1, gn1);
    gnorm_kernel<<<(NPIX2 + 255) / 256, 256, 0, stream>>>(lg2, gn2);
    // 3. trilinear upsample -> bf16 volume (2 px/thread, packed u32 stores)
    resize_kernel<<<(int)((NVOL2 + 255) / 256), 256, 0, stream>>>(cost, (unsigned*)buf0);
    // 4. LGA passes (bf16 volumes, bf16 normalized guidance, packed-f32 FMA).
    lga_tiled_kernel<0, false><<<lgrid, NTHR, 0, stream>>>(buf0, buf1, gn1, nullptr, nullptr, nullptr);
    lga_tiled_kernel<1, false><<<lgrid, NTHR, 0, stream>>>(buf1, buf0, gn1, nullptr, nullptr, rden);
    rcp_kernel<<<(NPIX4 + 255) / 256, 256, 0, stream>>>((float4*)rden);
    lga_tiled_kernel<0, true><<<lgrid, NTHR, 0, stream>>>(buf0, buf1, gn2, rden, nullptr, nullptr);
    lga_tiled_kernel<2, false><<<lgrid, NTHR, 0, stream>>>(buf1, nullptr, gn2, nullptr, Abuf, Sbuf);
    // 5. finish: normalize + expectation
    finish_kernel<<<(NPIX4 + 255) / 256, 256, 0, stream>>>((const float4*)Abuf, (const float4*)Sbuf, (float4*)out);
}

// Round 26
// 558.122 us; speedup vs baseline: 1.1721x; 1.1721x over previous
//
#include <hip/hip_runtime.h>
#include <hip/hip_bf16.h>
#include <math.h>

#define C_IN   32
#define D0     64
#define H0     96
#define W0     192
#define DD     193
#define HH     288
#define WW     576
#define NPIX   (HH*WW)            // 165888
#define NPIX2  (NPIX/2)           // 82944
#define NPIX4  (NPIX/4)           // 41472
#define NVOL   ((size_t)DD*NPIX)  // 32,016,384
#define NVOL2  (NVOL/2)
#define NCOST  (D0*H0*W0)         // 1,179,648
#define NCOST4 (NCOST/4)          // 294912

typedef float v2f __attribute__((ext_vector_type(2)));

__device__ __forceinline__ float2 f2(float x, float y) { float2 r; r.x = x; r.y = y; return r; }

// packed f32 FMA: d = a*b + c in one v_pk_fma_f32
__device__ __forceinline__ v2f fma2(v2f a, v2f b, v2f c) {
#if __has_builtin(__builtin_elementwise_fma)
    return __builtin_elementwise_fma(a, b, c);
#else
    asm("v_pk_fma_f32 %0, %1, %2, %0" : "+v"(c) : "v"(a), "v"(b));
    return c;
#endif
}

// bf16 storage helpers (RNE pack, shift unpack); compute stays f32
__device__ __forceinline__ unsigned short f2bf(float f) {
    unsigned u = __float_as_uint(f);
    unsigned r = (u + 0x7FFFu + ((u >> 16) & 1u)) >> 16;
    return (unsigned short)r;
}
__device__ __forceinline__ unsigned packbf(float x, float y) {
    return (unsigned)f2bf(x) | ((unsigned)f2bf(y) << 16);
}
__device__ __forceinline__ float bflo(unsigned u) { return __uint_as_float(u << 16); }
__device__ __forceinline__ float bfhi(unsigned u) { return __uint_as_float(u & 0xFFFF0000u); }

// ---------------- LDS-tiled conv3d, channel-split x4 (stable R17/R20/R24 version:
// f32 LDS staging. Measured vs alternatives: raw-prefetch pipeline spilled
// (170us), bf16 LDS staging lengthened the barrier-convoy critical path (190us);
// this form = 110us.)
#define CZC   8
#define CSL   (CZC + 2)
#define CROWS 6
#define CSTR  72

__global__ __launch_bounds__(256)
void conv3d_split_kernel(const float* __restrict__ x,
                         const float* __restrict__ w,
                         float* __restrict__ partial) {
    __shared__ __align__(16) float sb[2][CSL][CROWS][CSTR];
    const int tid = threadIdx.x;
    const int tx = tid & 63, ty = tid >> 6;
    const int wb = blockIdx.x * 64, hb = blockIdx.y * 4;
    const int zc = blockIdx.z & 7, part = blockIdx.z >> 3;
    const int z0 = zc * CZC;
    const int cbase = part * 8;

    float acc[CZC];
    #pragma unroll
    for (int i = 0; i < CZC; ++i) acc[i] = 0.f;

    const float4 f4zero = {0.f, 0.f, 0.f, 0.f};

    #define STAGE(b, ci)                                                          \
    {                                                                             \
        const float* xc = x + (size_t)(ci) * (D0 * H0 * W0);                      \
        _Pragma("unroll")                                                         \
        for (int t0 = 0; t0 < 4; ++t0) {                                          \
            int t = t0 * 256 + tid;                                               \
            if (t < 960) {                                                        \
                int sl = t / 96; int rem = t - sl * 96;                           \
                int r = rem >> 4, v = rem & 15;                                   \
                int zz = z0 - 1 + sl, hh = hb - 1 + r;                            \
                bool ok = (unsigned)zz < (unsigned)D0 && (unsigned)hh < (unsigned)H0; \
                float4 val = ok ? *(const float4*)(xc + ((size_t)zz * H0 + hh) * W0 + wb + 4 * v) \
                                : f4zero;                                         \
                *(float4*)&sb[b][sl][r][4 + 4 * v] = val;                         \
            }                                                                     \
        }                                                                         \
        if (tid < 120) {                                                          \
            int sl = tid / 12; int e = tid - sl * 12;                             \
            int r = e >> 1, side = e & 1;                                         \
            int zz = z0 - 1 + sl, hh = hb - 1 + r;                                \
            int ww = side ? wb + 64 : wb - 1;                                     \
            bool ok = (unsigned)zz < (unsigned)D0 && (unsigned)hh < (unsigned)H0  \
                      && (unsigned)ww < (unsigned)W0;                             \
            sb[b][sl][r][side ? 68 : 3] = ok ? xc[((size_t)zz * H0 + hh) * W0 + ww] : 0.f; \
        }                                                                         \
    }

    STAGE(0, cbase);
    __syncthreads();

    for (int c = 0; c < 8; ++c) {
        const int b = c & 1;
        if (c + 1 < 8) STAGE(b ^ 1, cbase + c + 1);

        const float* wc = w + (cbase + c) * 27;
        float wr[27];
        #pragma unroll
        for (int t = 0; t < 27; ++t) wr[t] = wc[t];

        #pragma unroll
        for (int sl = 0; sl < CSL; ++sl) {
            float tap[9];
            #pragma unroll
            for (int i = 0; i < 3; ++i)
                #pragma unroll
                for (int j = 0; j < 3; ++j)
                    tap[i * 3 + j] = sb[b][sl][ty + i][tx + 3 + j];
            if (sl < CZC) {
                float cs = 0.f;
                #pragma unroll
                for (int t = 0; t < 9; ++t) cs += wr[t] * tap[t];
                acc[sl] += cs;
            }
            if (sl >= 1 && sl - 1 < CZC) {
                float cs = 0.f;
                #pragma unroll
                for (int t = 0; t < 9; ++t) cs += wr[9 + t] * tap[t];
                acc[sl - 1] += cs;
            }
            if (sl >= 2) {
                float cs = 0.f;
                #pragma unroll
                for (int t = 0; t < 9; ++t) cs += wr[18 + t] * tap[t];
                acc[sl - 2] += cs;
            }
        }
        __syncthreads();
    }
    #undef STAGE

    float* po = partial + (size_t)part * NCOST;
    #pragma unroll
    for (int i = 0; i < CZC; ++i)
        po[((size_t)(z0 + i) * H0 + (hb + ty)) * W0 + (wb + tx)] = acc[i];
}

// ---------------- combine 4 partials -> cost (float4)
__global__ void combine_kernel(const float4* __restrict__ partial, float4* __restrict__ cost) {
    int i = blockIdx.x * 256 + threadIdx.x;
    if (i >= NCOST4) return;
    float4 a = partial[i];
    float4 b = partial[i + NCOST4];
    float4 c = partial[i + 2 * NCOST4];
    float4 d = partial[i + 3 * NCOST4];
    float4 r;
    r.x = a.x + b.x + c.x + d.x;
    r.y = a.y + b.y + c.y + d.y;
    r.z = a.z + b.z + c.z + d.z;
    r.w = a.w + b.w + c.w + d.w;
    cost[i] = r;
}

// ---------------- fused L1-norm + pre-normalize guidance to packed bf16
__global__ void gnorm_kernel(const float* __restrict__ g, unsigned* __restrict__ gn) {
    int p = blockIdx.x * 256 + threadIdx.x;   // pixel-pair index
    if (p >= NPIX2) return;
    float sx = 0.f, sy = 0.f;
    for (int c = 0; c < 75; ++c) {
        float2 v = *(const float2*)&g[(size_t)c * NPIX + 2 * p];
        sx += fabsf(v.x); sy += fabsf(v.y);
    }
    float ix = 1.0f / fmaxf(sx, 1e-12f);
    float iy = 1.0f / fmaxf(sy, 1e-12f);
    for (int c = 0; c < 75; ++c) {
        float2 v = *(const float2*)&g[(size_t)c * NPIX + 2 * p];
        gn[(size_t)c * NPIX2 + p] = packbf(v.x * ix, v.y * iy);
    }
}

// ---------------- trilinear resize cost f32 -> vol bf16, 2 px/thread (packed u32 store)
__global__ void resize_kernel(const float* __restrict__ cost, unsigned* __restrict__ out) {
    size_t idx2 = (size_t)blockIdx.x * 256 + threadIdx.x;
    if (idx2 >= NVOL2) return;
    size_t idx = idx2 * 2;
    int w = (int)(idx % WW);          // even; w+1 in same row (WW even)
    int t = (int)(idx / WW);
    int h = t % HH;
    int d = t / HH;

    float sd = fminf(fmaxf((d + 0.5f) * (64.0f / 193.0f) - 0.5f, 0.0f), 63.0f);
    int d0 = (int)floorf(sd); int d1 = min(d0 + 1, 63); float fd = sd - (float)d0;
    float sh = fminf(fmaxf((h + 0.5f) * (96.0f / 288.0f) - 0.5f, 0.0f), 95.0f);
    int h0 = (int)floorf(sh); int h1 = min(h0 + 1, 95); float fh = sh - (float)h0;

    float r01[2];
    #pragma unroll
    for (int k = 0; k < 2; ++k) {
        float sw = fminf(fmaxf((w + k + 0.5f) * (192.0f / 576.0f) - 0.5f, 0.0f), 191.0f);
        int w0 = (int)floorf(sw); int w1 = min(w0 + 1, 191); float fw = sw - (float)w0;
        #define CV(dz, hy, wx) cost[((size_t)(dz) * H0 + (hy)) * W0 + (wx)]
        float v000 = CV(d0, h0, w0), v001 = CV(d0, h0, w1);
        float v010 = CV(d0, h1, w0), v011 = CV(d0, h1, w1);
        float v100 = CV(d1, h0, w0), v101 = CV(d1, h0, w1);
        float v110 = CV(d1, h1, w0), v111 = CV(d1, h1, w1);
        #undef CV
        float a = v000 * (1.f - fw) + v001 * fw;
        float b = v010 * (1.f - fw) + v011 * fw;
        float c = v100 * (1.f - fw) + v101 * fw;
        float e = v110 * (1.f - fw) + v111 * fw;
        float lo = a * (1.f - fh) + b * fh;
        float hi = c * (1.f - fh) + e * fh;
        r01[k] = lo * (1.f - fd) + hi * fd;
    }
    out[idx2] = packbf(r01[0], r01[1]);
}

// ---------------- LDS-tiled LGA pass: R20/R24 configuration (measured local
// optimum: NDCH 2->112us, 3->96us, 4->111us per pass).
#define TW 64
#define TH 8
#define LROWS 12
#define LSTR  72
#define SLC_PAD 880
#define NTHR 256
#define DCHUNK 65
#define NDCH  3

template<int MODE, bool SCALED>
__global__ __launch_bounds__(NTHR, 2)
void lga_tiled_kernel(const unsigned short* __restrict__ in, unsigned short* __restrict__ out,
                      const unsigned* __restrict__ gn,
                      const float* __restrict__ inscale,
                      float* __restrict__ accAbuf, float* __restrict__ accSbuf) {
    __shared__ __align__(16) float sbuf[8][SLC_PAD];
    const int tid = threadIdx.x;
    const int tx = tid & 31, ty = tid >> 5;
    const int wb = blockIdx.x * TW, hb = blockIdx.y * TH;
    const int pix0 = (hb + ty) * WW + (wb + 2 * tx);
    const int ds = blockIdx.z * DCHUNK;
    const int de = min(ds + DCHUNK, DD);
    const int e0 = max(ds - 1, 0);
    const int emax = min(de, DD - 1);

    const bool hasB = (tid < 128);
    const bool hasE = (tid >= 128 && tid < 224);

    int slcA, vdstA; size_t vgoffA; bool vokA;
    {
        slcA = tid / 96; int u = tid - slcA * 96;
        int r = u >> 3, v = u & 7;
        int hh = hb - 2 + r;
        vokA = (unsigned)hh < (unsigned)HH;
        vgoffA = vokA ? (size_t)hh * WW + wb + 8 * v : 0;
        vdstA = r * LSTR + 4 + 8 * v;
    }
    int slcB = 0, vdstB = 0; size_t vgoffB = 0; bool vokB = false;
    if (hasB) {
        int t = tid + 256; slcB = t / 96; int u = t - slcB * 96;
        int r = u >> 3, v = u & 7;
        int hh = hb - 2 + r;
        vokB = (unsigned)hh < (unsigned)HH;
        vgoffB = vokB ? (size_t)hh * WW + wb + 8 * v : 0;
        vdstB = r * LSTR + 4 + 8 * v;
    }
    int slcE = 0, edstE = 0; size_t egoffE = 0; bool eokE = false;
    if (hasE) {
        int t = tid - 128; slcE = t / 24; int u = t - slcE * 24;
        int r = u >> 1, side = u & 1;
        int hh = hb - 2 + r;
        int gc = side ? wb + 64 : wb - 2;
        eokE = (unsigned)hh < (unsigned)HH && (unsigned)gc < (unsigned)WW;
        egoffE = eokE ? (size_t)hh * WW + gc : 0;
        edstE = r * LSTR + (side ? 68 : 2);
    }

    // inscale factors (only in the SCALED instantiation)
    float is8A[8], is8B[8]; float2 isE = f2(1.f, 1.f);
    if constexpr (SCALED) {
        #pragma unroll
        for (int j = 0; j < 8; ++j) { is8A[j] = 1.f; is8B[j] = 1.f; }
        if (vokA) {
            float4 a = *(const float4*)&inscale[vgoffA];
            float4 b = *(const float4*)&inscale[vgoffA + 4];
            is8A[0]=a.x; is8A[1]=a.y; is8A[2]=a.z; is8A[3]=a.w;
            is8A[4]=b.x; is8A[5]=b.y; is8A[6]=b.z; is8A[7]=b.w;
        }
        if (hasB && vokB) {
            float4 a = *(const float4*)&inscale[vgoffB];
            float4 b = *(const float4*)&inscale[vgoffB + 4];
            is8B[0]=a.x; is8B[1]=a.y; is8B[2]=a.z; is8B[3]=a.w;
            is8B[4]=b.x; is8B[5]=b.y; is8B[6]=b.z; is8B[7]=b.w;
        }
        if (hasE && eokE) isE = *(const float2*)&inscale[egoffE];
    }

    // --- pre-normalized guidance weights, (px0,px1) packed as v2f
    const int gp = pix0 >> 1;
    v2f g0[25], g1[25], g2[25];
    #pragma unroll
    for (int c = 0; c < 25; ++c) {
        unsigned u = gn[(size_t)c * NPIX2 + gp];
        g0[c] = (v2f){bflo(u), bfhi(u)};
    }
    #pragma unroll
    for (int c = 0; c < 25; ++c) {
        unsigned u = gn[(size_t)(25 + c) * NPIX2 + gp];
        g1[c] = (v2f){bflo(u), bfhi(u)};
    }
    #pragma unroll
    for (int c = 0; c < 25; ++c) {
        unsigned u = gn[(size_t)(50 + c) * NPIX2 + gp];
        g2[c] = (v2f){bflo(u), bfhi(u)};
    }

    // pending RAW bf16 loads
    uint4 avA = {0u,0u,0u,0u}, avB = {0u,0u,0u,0u};
    unsigned aeE = 0u;

    #define LOADQUAD(eb)                                                          \
    {                                                                             \
        if (vokA && (eb) + slcA <= emax)                                          \
            avA = *(const uint4*)(in + (size_t)((eb) + slcA) * NPIX + vgoffA);    \
        if (hasB && vokB && (eb) + slcB <= emax)                                  \
            avB = *(const uint4*)(in + (size_t)((eb) + slcB) * NPIX + vgoffB);    \
        if (hasE && eokE && (eb) + slcE <= emax)                                  \
            aeE = *(const unsigned*)(in + (size_t)((eb) + slcE) * NPIX + egoffE); \
    }

    LOADQUAD(e0);

    v2f accA = {0.f, 0.f}, accB = {0.f, 0.f};
    float2 aloc = f2(0.f, 0.f), sloc = f2(0.f, 0.f);
    unsigned* ou32 = (unsigned*)out;

    #define EMIT(n, vx, vy)                                                       \
    {                                                                             \
        if constexpr (MODE == 0) {                                                \
            ou32[((size_t)(n) * NPIX + pix0) >> 1] = packbf((vx), (vy));          \
        } else if constexpr (MODE == 1) {                                         \
            float ex_ = __expf(-(vx)), ey_ = __expf(-(vy));                       \
            ou32[((size_t)(n) * NPIX + pix0) >> 1] = packbf(ex_, ey_);            \
            sloc.x += ex_; sloc.y += ey_;                                         \
        } else {                                                                  \
            aloc.x += (vx) * (float)(n); aloc.y += (vy) * (float)(n);             \
            sloc.x += fabsf(vx); sloc.y += fabsf(vy);                             \
        }                                                                         \
    }

    for (int e = e0; e <= emax; e += 4) {
        // 1. commit pending quad: bf16->f32 (+inscale) at consume time
        {
            float v0 = bflo(avA.x), v1 = bfhi(avA.x), v2 = bflo(avA.y), v3 = bfhi(avA.y);
            float v4 = bflo(avA.z), v5 = bfhi(avA.z), v6 = bflo(avA.w), v7 = bfhi(avA.w);
            if constexpr (SCALED) {
                v0 *= is8A[0]; v1 *= is8A[1]; v2 *= is8A[2]; v3 *= is8A[3];
                v4 *= is8A[4]; v5 *= is8A[5]; v6 *= is8A[6]; v7 *= is8A[7];
            }
            float* sp = &sbuf[(e + slcA) & 7][vdstA];
            *(float4*)sp       = make_float4(v0, v1, v2, v3);
            *(float4*)(sp + 4) = make_float4(v4, v5, v6, v7);
        }
        if (hasB) {
            float v0 = bflo(avB.x), v1 = bfhi(avB.x), v2 = bflo(avB.y), v3 = bfhi(avB.y);
            float v4 = bflo(avB.z), v5 = bfhi(avB.z), v6 = bflo(avB.w), v7 = bfhi(avB.w);
            if constexpr (SCALED) {
                v0 *= is8B[0]; v1 *= is8B[1]; v2 *= is8B[2]; v3 *= is8B[3];
                v4 *= is8B[4]; v5 *= is8B[5]; v6 *= is8B[6]; v7 *= is8B[7];
            }
            float* sp = &sbuf[(e + slcB) & 7][vdstB];
            *(float4*)sp       = make_float4(v0, v1, v2, v3);
            *(float4*)(sp + 4) = make_float4(v4, v5, v6, v7);
        }
        if (hasE) {
            float v0 = bflo(aeE), v1 = bfhi(aeE);
            if constexpr (SCALED) { v0 *= isE.x; v1 *= isE.y; }
            float* sp = &sbuf[(e + slcE) & 7][edstE];
            *(float2*)sp = f2(v0, v1);
        }
        // 2. issue RAW loads for the next quad
        LOADQUAD(e + 4);
        // 3. LDS drain + raw barrier (no vmcnt drain)
        asm volatile("s_waitcnt lgkmcnt(0)" ::: "memory");
        __builtin_amdgcn_s_barrier();
        // 4. compute up to 4 slices (packed-f32: 3 pk_fma per tap for 2 px x 3 convs)
        #pragma unroll
        for (int ss = 0; ss < 4; ++ss) {
            int f = e + ss;
            if (f > emax) break;
            const float* base = sbuf[f & 7] + ty * LSTR + 2 * tx + 2;
            v2f a0 = {0.f, 0.f}, a1 = {0.f, 0.f}, a2 = {0.f, 0.f};
            #pragma unroll
            for (int i = 0; i < 5; ++i) {
                const float* rp = base + i * LSTR;
                v2f W01 = *(const v2f*)(rp);
                v2f W23 = *(const v2f*)(rp + 2);
                v2f W45 = *(const v2f*)(rp + 4);
                v2f W12 = {rp[1], rp[2]};
                v2f W34 = {rp[3], rp[4]};
                int t = i * 5;
                a0 = fma2(g0[t],     W01, a0); a1 = fma2(g1[t],     W01, a1); a2 = fma2(g2[t],     W01, a2);
                a0 = fma2(g0[t + 1], W12, a0); a1 = fma2(g1[t + 1], W12, a1); a2 = fma2(g2[t + 1], W12, a2);
                a0 = fma2(g0[t + 2], W23, a0); a1 = fma2(g1[t + 2], W23, a1); a2 = fma2(g2[t + 2], W23, a2);
                a0 = fma2(g0[t + 3], W34, a0); a1 = fma2(g1[t + 3], W34, a1); a2 = fma2(g2[t + 3], W34, a2);
                a0 = fma2(g0[t + 4], W45, a0); a1 = fma2(g1[t + 4], W45, a1); a2 = fma2(g2[t + 4], W45, a2);
            }
            int n = f - 1;
            if (n >= ds && n < de) {
                v2f rr = accA + a2;
                EMIT(n, rr.x, rr.y);
            }
            accA = accB + a1;
            accB = a0;
        }
    }
    if (de == DD) {
        EMIT(DD - 1, accA.x, accA.y);  // slice DD is zero-pad: no c2 term
    }
    #undef EMIT
    #undef LOADQUAD

    if constexpr (MODE == 1) {
        atomicAdd(&accSbuf[pix0], sloc.x);
        atomicAdd(&accSbuf[pix0 + 1], sloc.y);
    } else if constexpr (MODE == 2) {
        atomicAdd(&accAbuf[pix0], aloc.x);
        atomicAdd(&accAbuf[pix0 + 1], aloc.y);
        atomicAdd(&accSbuf[pix0], sloc.x);
        atomicAdd(&accSbuf[pix0 + 1], sloc.y);
    }
}

// ---------------- reciprocal in place (float4)
__global__ void rcp_kernel(float4* __restrict__ v) {
    int p = blockIdx.x * 256 + threadIdx.x;
    if (p >= NPIX4) return;
    float4 a = v[p];
    a.x = 1.0f / a.x; a.y = 1.0f / a.y; a.z = 1.0f / a.z; a.w = 1.0f / a.w;
    v[p] = a;
}

// ---------------- finish: out = A / max(S, eps) (float4)
__global__ void finish_kernel(const float4* __restrict__ A, const float4* __restrict__ S,
                              float4* __restrict__ out) {
    int p = blockIdx.x * 256 + threadIdx.x;
    if (p >= NPIX4) return;
    float4 a = A[p], s = S[p];
    float4 r;
    r.x = a.x / fmaxf(s.x, 1e-12f);
    r.y = a.y / fmaxf(s.y, 1e-12f);
    r.z = a.z / fmaxf(s.z, 1e-12f);
    r.w = a.w / fmaxf(s.w, 1e-12f);
    out[p] = r;
}

extern "C" void kernel_launch(void* const* d_in, const int* in_sizes, int n_in,
                              void* d_out, int out_size, void* d_ws, size_t ws_size,
                              hipStream_t stream) {
    const float* x    = (const float*)d_in[0];
    const float* lg1  = (const float*)d_in[1];
    const float* lg2  = (const float*)d_in[2];
    const float* cw   = (const float*)d_in[3];
    float* out = (float*)d_out;

    float* ws   = (float*)d_ws;
    // bf16 volumes: NVOL ushorts = NVOL/2 float slots each
    unsigned short* buf0 = (unsigned short*)ws;
    unsigned short* buf1 = (unsigned short*)(ws + NVOL / 2);
    float* cost = ws + NVOL;           // after both bf16 volumes
    float* rden = cost + NCOST;
    float* Abuf = rden + NPIX;
    float* Sbuf = Abuf + NPIX;
    unsigned* gn1 = (unsigned*)(Sbuf + NPIX);
    unsigned* gn2 = gn1 + (size_t)75 * NPIX2;
    // conv partials (4 x NCOST f32) alias buf1's region (dead before lga#1 writes buf1)
    float* partials = (float*)buf1;

    const dim3 lgrid(WW / TW, HH / TH, NDCH);

    // 0. zero the atomic accumulators
    hipMemsetAsync(rden, 0, NPIX * sizeof(float), stream);
    hipMemsetAsync(Abuf, 0, NPIX * sizeof(float), stream);
    hipMemsetAsync(Sbuf, 0, NPIX * sizeof(float), stream);

    // 1. conv3d (channel-split x4) + combine
    conv3d_split_kernel<<<dim3(W0 / 64, H0 / 4, (D0 / CZC) * 4), 256, 0, stream>>>(x, cw, partials);
    combine_kernel<<<(NCOST4 + 255) / 256, 256, 0, stream>>>((const float4*)partials, (float4*)cost);
    // 2. fused L1-norm + bf16 pre-normalized guidance
    gnorm_kernel<<<(NPIX2 + 255) / 256, 256, 0, stream>>>(lg1, gn1);
    gnorm_kernel<<<(NPIX2 + 255) / 256, 256, 0, stream>>>(lg2, gn2);
    // 3. trilinear upsample -> bf16 volume (2 px/thread, packed u32 stores)
    resize_kernel<<<(int)((NVOL2 + 255) / 256), 256, 0, stream>>>(cost, (unsigned*)buf0);
    // 4. LGA passes (bf16 volumes, bf16 normalized guidance, packed-f32 FMA).
    lga_tiled_kernel<0, false><<<lgrid, NTHR, 0, stream>>>(buf0, buf1, gn1, nullptr, nullptr, nullptr);
    lga_tiled_kernel<1, false><<<lgrid, NTHR, 0, stream>>>(buf1, buf0, gn1, nullptr, nullptr, rden);
    rcp_kernel<<<(NPIX4 + 255) / 256, 256, 0, stream>>>((float4*)rden);
    lga_tiled_kernel<0, true><<<lgrid, NTHR, 0, stream>>>(buf0, buf1, gn2, rden, nullptr, nullptr);
    lga_tiled_kernel<2, false><<<lgrid, NTHR, 0, stream>>>(buf1, nullptr, gn2, nullptr, Abuf, Sbuf);
    // 5. finish: normalize + expectation
    finish_kernel<<<(NPIX4 + 255) / 256, 256, 0, stream>>>((const float4*)Abuf, (const float4*)Sbuf, (float4*)out);
}